// Round 14
// baseline (149.833 us; speedup 1.0000x reference)
//
#include <hip/hip_runtime.h>
#include <hip/hip_bf16.h>
#include <math.h>

typedef __hip_bfloat16 bf16;
using s8v = __attribute__((ext_vector_type(8))) short;   // 8 bf16 (4 VGPRs)
using f4v = __attribute__((ext_vector_type(4))) float;   // 4 fp32
using u32x2 = __attribute__((ext_vector_type(2))) unsigned int;

#if __has_builtin(__builtin_amdgcn_exp2f)
#define EXP2(x) __builtin_amdgcn_exp2f(x)
#else
#define EXP2(x) exp2f(x)
#endif

__device__ __forceinline__ float bfb2f(unsigned short u) {
    return __uint_as_float(((unsigned int)u) << 16);
}
// RNE (output / ws paths)
__device__ __forceinline__ unsigned short f2bfb(float f) {
    unsigned int u = __float_as_uint(f);
    unsigned int r = (u + 0x7fffu + ((u >> 16) & 1u)) >> 16;
    return (unsigned short)r;
}
// RNE pack: 2 fp32 -> u32 of 2 bf16 (bit-identical to scalar f2bfb pair)
__device__ __forceinline__ unsigned int packbf2_rne(float a, float b) {
    return (unsigned int)f2bfb(a) | ((unsigned int)f2bfb(b) << 16);
}
// round-half-up pack via v_perm_b32 (3 VALU) — P path only (exp outputs)
__device__ __forceinline__ unsigned int packbf2(float a, float b) {
    return __builtin_amdgcn_perm(__float_as_uint(b) + 0x8000u,
                                 __float_as_uint(a) + 0x8000u,
                                 0x07060302u);
}
// 4 u32 words -> 8 bf16 fragment
__device__ __forceinline__ s8v mk8(unsigned int a, unsigned int b,
                                   unsigned int c, unsigned int d) {
    union { unsigned int u[4]; s8v v; } x;
    x.u[0] = a; x.u[1] = b; x.u[2] = c; x.u[3] = d;
    return x.v;
}
// permlane32_swap then permlane16_swap on a register pair (gfx950 builtins,
// fi=false bound_ctrl=false). Verified r22 (absmax unchanged).
__device__ __forceinline__ void plswap(unsigned int& a, unsigned int& b) {
    u32x2 t = __builtin_amdgcn_permlane32_swap(a, b, false, false);
    u32x2 u = __builtin_amdgcn_permlane16_swap(t.x, t.y, false, false);
    a = u.x;
    b = u.y;
}

// async global->LDS, 16B per lane: LDS dest = wave-uniform base + lane*16,
// global src = per-lane address (m173 pattern: src addresses encode layout).
__device__ __forceinline__ void gload_lds16(const void* g, void* l) {
    __builtin_amdgcn_global_load_lds(
        (const __attribute__((address_space(1))) unsigned int*)g,
        (__attribute__((address_space(3))) unsigned int*)l, 16, 0, 0);
}

// Per-block input-dtype sniff (proved rounds 4-10: inputs are fp32).
// Coalesced (r16): 4 x uint4 per lane, same decision function.
__device__ __forceinline__ int sniff_fp32(const void* p, int tid, int* s_flag)
{
    if (tid == 0) *s_flag = 0;
    __syncthreads();
    const uint4* u = (const uint4*)p;
    int local = 0;
    #pragma unroll
    for (int i = 0; i < 4; i++) {
        const uint4 v = u[i * 256 + tid];
        if ((v.x & 0x7F80u) == 0x7F80u) local = 1;
        if ((v.y & 0x7F80u) == 0x7F80u) local = 1;
        if ((v.z & 0x7F80u) == 0x7F80u) local = 1;
        if ((v.w & 0x7F80u) == 0x7F80u) local = 1;
    }
    if (local) atomicOr(s_flag, 1);
    __syncthreads();
    return *s_flag;
}

// ---------------------------------------------------------------------------
// Kernel 0: one-time prep. UNCHANGED from r24.
// ---------------------------------------------------------------------------
__global__ __launch_bounds__(256)
void k_prep(const void* __restrict__ x, const void* __restrict__ Wqkv,
            const void* __restrict__ bqkv, const void* __restrict__ Wout,
            const void* __restrict__ bout,
            bf16* __restrict__ wqkvT, bf16* __restrict__ woutT,
            float* __restrict__ bq_f, float* __restrict__ bo_f,
            bf16* __restrict__ xb)
{
    __shared__ int sf;
    const int bid = blockIdx.x;
    const int tid = threadIdx.x;
    if (bid < 768) {
        const int f = sniff_fp32(Wqkv, tid, &sf);
        unsigned short v = f ? f2bfb(((const float*)Wqkv)[(size_t)tid * 768 + bid])
                             : ((const unsigned short*)Wqkv)[(size_t)tid * 768 + bid];
        ((unsigned short*)wqkvT)[(size_t)bid * 256 + tid] = v;
        if (bid < 12) {
            const int i = bid * 256 + tid;
            bq_f[i] = f ? ((const float*)bqkv)[i]
                        : bfb2f(((const unsigned short*)bqkv)[i]);
        }
    } else if (bid < 1024) {
        const int n = bid - 768;
        const int f = sniff_fp32(Wout, tid, &sf);
        unsigned short v = f ? f2bfb(((const float*)Wout)[(size_t)tid * 256 + n])
                             : ((const unsigned short*)Wout)[(size_t)tid * 256 + n];
        ((unsigned short*)woutT)[(size_t)n * 256 + tid] = v;
        if (n == 0)
            bo_f[tid] = f ? ((const float*)bout)[tid]
                          : bfb2f(((const unsigned short*)bout)[tid]);
    } else {
        // x: 4,194,304 elems; 1024 blocks x 256 thr x 16 elems
        const int f = sniff_fp32(x, tid, &sf);
        if (f) {
            // coalesced: lane-stride-16B float4 reads, lane-stride-8B stores
            const size_t cb = (size_t)(bid - 1024) * 4096;
            #pragma unroll
            for (int i = 0; i < 4; i++) {
                const size_t e = cb + (size_t)i * 1024 + tid * 4;
                const float4 v = *(const float4*)((const float*)x + e);
                ushort4 o4;
                o4.x = f2bfb(v.x);
                o4.y = f2bfb(v.y);
                o4.z = f2bfb(v.z);
                o4.w = f2bfb(v.w);
                *(ushort4*)((unsigned short*)xb + e) = o4;
            }
        } else {
            const size_t base = (size_t)(bid - 1024) * 4096 + (size_t)tid * 16;
            const uint4* xu = (const uint4*)((const unsigned short*)x + base);
            uint4* dp = (uint4*)((unsigned short*)xb + base);
            dp[0] = xu[0];
            dp[1] = xu[1];
        }
    }
}

// ---------------------------------------------------------------------------
// Kernel 1 (MFMA): qkv = xb @ Wqkv + bqkv ; RoPE(q,k).
// q scale folds log2(e) (r24). UNCHANGED. grid = (12, 128).
// ---------------------------------------------------------------------------
__global__ __launch_bounds__(256)
void k_qkv_rope(const bf16* __restrict__ xb, const bf16* __restrict__ wqkvT,
                const float* __restrict__ bq_f,
                bf16* __restrict__ q_ws, bf16* __restrict__ k_ws,
                bf16* __restrict__ vT_ws)
{
    __shared__ __align__(16) unsigned short Bls[4][8][512];  // 32 KB B panel
    __shared__ __align__(16) unsigned short Tls[4][1536];    // 12 KB

    const int tid = threadIdx.x;
    const int bx = blockIdx.x;   // N tile 0..11
    const int by = blockIdx.y;   // 128-row M tile 0..127
    const int n0 = bx * 64;

    const int w    = tid >> 6;
    const int lane = tid & 63;
    const int col  = lane & 15;
    const int quad = lane >> 4;
    const int which = n0 >> 8;             // 0=q,1=k,2=v (block-uniform)
    const int b     = (by * 128) >> 11;    // batch (block-uniform)
    unsigned short* Tw = Tls[w];

    // stage B panel: wave w stages c=w, all kk.
    #pragma unroll
    for (int kk = 0; kk < 8; kk++)
        gload_lds16((const unsigned short*)wqkvT +
                        (size_t)(n0 + w * 16 + col) * 256 + kk * 32 + quad * 8,
                    &Bls[w][kk][0]);
    __syncthreads();

    const int T0 = by * 128 + w * 32;      // wave's 32-row band

    f4v acc[2][4] = {{{0.f,0.f,0.f,0.f}, {0.f,0.f,0.f,0.f},
                      {0.f,0.f,0.f,0.f}, {0.f,0.f,0.f,0.f}},
                     {{0.f,0.f,0.f,0.f}, {0.f,0.f,0.f,0.f},
                      {0.f,0.f,0.f,0.f}, {0.f,0.f,0.f,0.f}}};

    #pragma unroll
    for (int kk = 0; kk < 8; kk++) {
        const s8v av0 = *(const s8v*)((const unsigned short*)xb +
                        (size_t)(T0 + col) * 256 + kk * 32 + quad * 8);
        const s8v av1 = *(const s8v*)((const unsigned short*)xb +
                        (size_t)(T0 + 16 + col) * 256 + kk * 32 + quad * 8);
        #pragma unroll
        for (int c = 0; c < 4; c++) {
            const s8v bv = *(const s8v*)&Bls[c][kk][lane * 8];
            acc[0][c] = __builtin_amdgcn_mfma_f32_16x16x32_bf16(av0, bv, acc[0][c], 0, 0, 0);
            acc[1][c] = __builtin_amdgcn_mfma_f32_16x16x32_bf16(av1, bv, acc[1][c], 0, 0, 0);
        }
    }

    #pragma unroll
    for (int g = 0; g < 2; g++) {
        const int t_base = ((by * 128) & 2047) + w * 32 + g * 16;

        if (which == 2) {
            // V: LDS patch [n_local][24] (packed b64 RNE), then 32B rows of vT
            #pragma unroll
            for (int c = 0; c < 4; c++) {
                const int nl = c * 16 + col;
                const float bias = bq_f[n0 + nl];
                uint2 ww;
                ww.x = packbf2_rne(acc[g][c][0] + bias, acc[g][c][1] + bias);
                ww.y = packbf2_rne(acc[g][c][2] + bias, acc[g][c][3] + bias);
                *(uint2*)(Tw + nl * 24 + quad * 4) = ww;
            }
            const int ng = n0 + lane;
            const int h = (ng & 255) >> 5;
            const int d = ng & 31;
            const s8v t0 = *(const s8v*)&Tw[lane * 24];
            const s8v t1 = *(const s8v*)&Tw[lane * 24 + 8];
            unsigned short* dp = (unsigned short*)vT_ws +
                ((size_t)(b * 8 + h) * 32 + d) * 2048 + t_base;
            *(s8v*)dp = t0;
            *(s8v*)(dp + 8) = t1;
        } else {
            // q/k: RoPE in regs, LDS patch [t_local][80], 32B stores
            #pragma unroll
            for (int c = 0; c < 4; c++) {
                const int nl = c * 16 + col;
                const int d = (n0 + nl) & 31;
                const float bias = bq_f[n0 + nl];
                const float frev = __expf(-0.28782314f * (float)(d & ~1))
                                 * 0.15915494309189535f;
                #pragma unroll
                for (int r = 0; r < 4; r++) {
                    const float v = acc[g][c][r] + bias;
                    const float vp = __shfl_xor(v, 1);
                    const int t = t_base + quad * 4 + r;
                    float rev = (float)t * frev;
                    rev -= floorf(rev);
                    const float ang = rev * 6.283185307179586f;
                    const float sn = __sinf(ang);
                    const float cs = __cosf(ang);
                    float o = (d & 1) ? (v * cs + vp * sn)
                                      : (v * cs - vp * sn);
                    // q: 1/sqrt(32) * log2(e) so attn uses bare 2^x
                    if (which == 0) o *= 0.25503487021228657f;
                    Tw[(quad * 4 + r) * 80 + nl] = f2bfb(o);
                }
            }
            const int row = lane >> 2;
            const int ch  = lane & 3;
            const int ng  = n0 + ch * 16;
            const int h   = (ng & 255) >> 5;
            const int d   = ng & 31;
            const int t   = t_base + row;
            const s8v t0 = *(const s8v*)&Tw[row * 80 + ch * 16];
            const s8v t1 = *(const s8v*)&Tw[row * 80 + ch * 16 + 8];
            unsigned short* dp = (unsigned short*)(which ? k_ws : q_ws) +
                ((size_t)(b * 8 + h) * 2048 + t) * 32 + d;
            *(s8v*)dp = t0;
            *(s8v*)(dp + 8) = t1;
        }
        // Tls reuse across g is safe: wave-private buffer, DS ops in-order.
    }
}

// ---------------------------------------------------------------------------
// Kernel 2: causal flash attention. r25: 128-q BLOCKS (4 waves x 32 q).
// r24's DS-issue floor (32 redundant frag reads x 33792 block-iters = 26us)
// is the wall; halve block-iters by giving each wave 32 q-rows (2 Q frags,
// two INDEPENDENT compute chains -> better ILP than r20's serial pair).
// grid = 1024 (16 q-tiles x 64 bh): ALL blocks co-resident from t=0
// (4096 waves <= capacity), zero dispatch tail; longest-first mb ordering
// balances per-CU work. K/V traffic halves (270->139 MB). Waves skip
// fully-masked diagonal-adjacent tiles (still stage + barrier).
// Differences vs r20's failed 32q attempt: 4-wave blocks (not 2), 16
// waves/CU (not 14), dual independent chains per iter.
// LDS 16 KB unchanged. grid = 1024 x 256.
// ---------------------------------------------------------------------------
__global__ __launch_bounds__(256, 4)
void k_attn(const bf16* __restrict__ q_ws, const bf16* __restrict__ k_ws,
            const bf16* __restrict__ vT_ws, bf16* __restrict__ ctx)
{
    // KV fragment cache: [dbuf][chunk][1024B]. chunks 0-3 = kf0..3,
    // 4-7 = v00,v10,v01,v11. Frag read = base + lane*16 (linear).
    __shared__ __align__(16) unsigned short KVls[2][8][512];  // 16 KB

    const int tid  = threadIdx.x;
    const int w    = tid >> 6;
    const int lane = tid & 63;
    const int col  = lane & 15;
    const int quad = lane >> 4;

    const int idx = blockIdx.x;           // 0..1023
    const int bh  = idx & 63;             // batch*8+head; XCD pin = bh&7
    const int mb  = 15 - (idx >> 6);      // 128-q tile, longest blocks first
    const int T0  = mb * 128 + w * 32;    // wave's 32-row band

    const bf16* qb = q_ws  + (size_t)bh * 65536;
    const bf16* kb = k_ws  + (size_t)bh * 65536;
    const bf16* vb = vT_ws + (size_t)bh * 65536;

    const bf16* kg = kb + (size_t)(w * 16 + col) * 32 + quad * 8;
    const bf16* vg = vb + (size_t)(col + (w & 1) * 16) * 2048
                        + (w >> 1) * 32 + quad * 8;

    const s8v qa0 = *(const s8v*)(qb + (size_t)(T0 + col) * 32 + quad * 8);
    const s8v qa1 = *(const s8v*)(qb + (size_t)(T0 + 16 + col) * 32 + quad * 8);

    f4v o00 = {0.f,0.f,0.f,0.f}, o01 = {0.f,0.f,0.f,0.f};
    f4v o10 = {0.f,0.f,0.f,0.f}, o11 = {0.f,0.f,0.f,0.f};
    float lp0[4] = {0.f,0.f,0.f,0.f};
    float lp1[4] = {0.f,0.f,0.f,0.f};

    // prologue: stage tile 0 into buf 0
    gload_lds16(kg, &KVls[0][w][0]);
    gload_lds16(vg, &KVls[0][4 + w][0]);
    __syncthreads();

    const int ktmax = 2 * mb + 1;         // s-tiles 0..ktmax (64 each)
    int cur = 0;
    for (int kt = 0; kt <= ktmax; kt++) {
        const int s0 = kt * 64;

        // stage next tile into the other buffer (all waves, every iter)
        if (kt < ktmax) {
            gload_lds16(kg + (size_t)(kt + 1) * 2048, &KVls[cur ^ 1][w][0]);
            gload_lds16(vg + (kt + 1) * 64,           &KVls[cur ^ 1][4 + w][0]);
        }

        const bool a0 = (s0 <= T0 + 15);       // group 0 has unmasked cols
        const bool a1 = (s0 <= T0 + 31);       // group 1 (a0 implies a1)

        if (a1) {
            // fragment reads: linear lane*16, conflict-free
            const s8v kf0 = *(const s8v*)&KVls[cur][0][lane * 8];
            const s8v kf1 = *(const s8v*)&KVls[cur][1][lane * 8];
            const s8v kf2 = *(const s8v*)&KVls[cur][2][lane * 8];
            const s8v kf3 = *(const s8v*)&KVls[cur][3][lane * 8];
            const s8v v00 = *(const s8v*)&KVls[cur][4][lane * 8];
            const s8v v10 = *(const s8v*)&KVls[cur][5][lane * 8];
            const s8v v01 = *(const s8v*)&KVls[cur][6][lane * 8];
            const s8v v11 = *(const s8v*)&KVls[cur][7][lane * 8];

            const f4v z = {0.f, 0.f, 0.f, 0.f};

            // ---- group 1 (always active when a1) ----
            {
                f4v s[4];
                s[0] = __builtin_amdgcn_mfma_f32_16x16x32_bf16(kf0, qa1, z, 0, 0, 0);
                s[1] = __builtin_amdgcn_mfma_f32_16x16x32_bf16(kf1, qa1, z, 0, 0, 0);
                s[2] = __builtin_amdgcn_mfma_f32_16x16x32_bf16(kf2, qa1, z, 0, 0, 0);
                s[3] = __builtin_amdgcn_mfma_f32_16x16x32_bf16(kf3, qa1, z, 0, 0, 0);
                if (s0 + 63 > T0 + 16) {       // diagonal band for group 1
                    #pragma unroll
                    for (int c = 0; c < 4; c++) {
                        const int sbase = s0 + c * 16 + quad * 4;
                        #pragma unroll
                        for (int r = 0; r < 4; r++)
                            if (sbase + r > T0 + 16 + col) s[c][r] = -INFINITY;
                    }
                }
                unsigned int pw[8];
                #pragma unroll
                for (int c = 0; c < 4; c++) {
                    const float p0 = EXP2(s[c][0]);
                    const float p1 = EXP2(s[c][1]);
                    const float p2 = EXP2(s[c][2]);
                    const float p3 = EXP2(s[c][3]);
                    lp1[0] += p0; lp1[1] += p1; lp1[2] += p2; lp1[3] += p3;
                    pw[c * 2]     = packbf2(p0, p1);
                    pw[c * 2 + 1] = packbf2(p2, p3);
                }
                plswap(pw[0], pw[2]);
                plswap(pw[1], pw[3]);
                plswap(pw[4], pw[6]);
                plswap(pw[5], pw[7]);
                const s8v pa0 = mk8(pw[0], pw[1], pw[2], pw[3]);
                const s8v pa1 = mk8(pw[4], pw[5], pw[6], pw[7]);
                o10 = __builtin_amdgcn_mfma_f32_16x16x32_bf16(pa0, v00, o10, 0, 0, 0);
                o11 = __builtin_amdgcn_mfma_f32_16x16x32_bf16(pa0, v10, o11, 0, 0, 0);
                o10 = __builtin_amdgcn_mfma_f32_16x16x32_bf16(pa1, v01, o10, 0, 0, 0);
                o11 = __builtin_amdgcn_mfma_f32_16x16x32_bf16(pa1, v11, o11, 0, 0, 0);
            }

            // ---- group 0 ----
            if (a0) {
                f4v s[4];
                s[0] = __builtin_amdgcn_mfma_f32_16x16x32_bf16(kf0, qa0, z, 0, 0, 0);
                s[1] = __builtin_amdgcn_mfma_f32_16x16x32_bf16(kf1, qa0, z, 0, 0, 0);
                s[2] = __builtin_amdgcn_mfma_f32_16x16x32_bf16(kf2, qa0, z, 0, 0, 0);
                s[3] = __builtin_amdgcn_mfma_f32_16x16x32_bf16(kf3, qa0, z, 0, 0, 0);
                if (s0 + 63 > T0) {            // diagonal band for group 0
                    #pragma unroll
                    for (int c = 0; c < 4; c++) {
                        const int sbase = s0 + c * 16 + quad * 4;
                        #pragma unroll
                        for (int r = 0; r < 4; r++)
                            if (sbase + r > T0 + col) s[c][r] = -INFINITY;
                    }
                }
                unsigned int pw[8];
                #pragma unroll
                for (int c = 0; c < 4; c++) {
                    const float p0 = EXP2(s[c][0]);
                    const float p1 = EXP2(s[c][1]);
                    const float p2 = EXP2(s[c][2]);
                    const float p3 = EXP2(s[c][3]);
                    lp0[0] += p0; lp0[1] += p1; lp0[2] += p2; lp0[3] += p3;
                    pw[c * 2]     = packbf2(p0, p1);
                    pw[c * 2 + 1] = packbf2(p2, p3);
                }
                plswap(pw[0], pw[2]);
                plswap(pw[1], pw[3]);
                plswap(pw[4], pw[6]);
                plswap(pw[5], pw[7]);
                const s8v pa0 = mk8(pw[0], pw[1], pw[2], pw[3]);
                const s8v pa1 = mk8(pw[4], pw[5], pw[6], pw[7]);
                o00 = __builtin_amdgcn_mfma_f32_16x16x32_bf16(pa0, v00, o00, 0, 0, 0);
                o01 = __builtin_amdgcn_mfma_f32_16x16x32_bf16(pa0, v10, o01, 0, 0, 0);
                o00 = __builtin_amdgcn_mfma_f32_16x16x32_bf16(pa1, v01, o00, 0, 0, 0);
                o01 = __builtin_amdgcn_mfma_f32_16x16x32_bf16(pa1, v11, o01, 0, 0, 0);
            }
        }

        // barrier: (a) drains this wave's stage loads (vmcnt) so next iter's
        // frag reads are safe; (b) orders buffer reuse across waves.
        __syncthreads();
        cur ^= 1;
    }

    // Row sums: lane-local partials -> cross-quad reduce (per group).
    float rs0 = lp0[0] + lp0[1] + lp0[2] + lp0[3];
    rs0 += __shfl_xor(rs0, 16);
    rs0 += __shfl_xor(rs0, 32);
    float rs1 = lp1[0] + lp1[1] + lp1[2] + lp1[3];
    rs1 += __shfl_xor(rs1, 16);
    rs1 += __shfl_xor(rs1, 32);

    const int b = bh >> 3;
    const int h = bh & 7;
    unsigned short* cp = (unsigned short*)ctx;
    #pragma unroll
    for (int g = 0; g < 2; g++) {
        const float rs = g ? rs1 : rs0;
        const int T0g = T0 + g * 16;
        #pragma unroll
        for (int r = 0; r < 4; r++) {
            // output row q = quad*4+r; its row-sum lives in lane quad*4+r
            const float inv = 1.0f / __shfl(rs, quad * 4 + r);
            const float e0 = (g ? o10[r] : o00[r]) * inv;
            const float e1 = (g ? o11[r] : o01[r]) * inv;
            const int t = T0g + quad * 4 + r;
            unsigned short* dst = cp + (size_t)(b * 2048 + t) * 256 + h * 32;
            dst[col]      = f2bfb(e0);
            dst[col + 16] = f2bfb(e1);
        }
    }
}

// ---------------------------------------------------------------------------
// Kernel 3 (MFMA): out = ctx @ Wout + bout (M=16384,N=256,K=256), fp32 out.
// 32-row waves (r19). UNCHANGED. grid = (4, 128).
// ---------------------------------------------------------------------------
__global__ __launch_bounds__(256)
void k_outproj(const bf16* __restrict__ ctx, const bf16* __restrict__ woutT,
               const float* __restrict__ bo_f, float* __restrict__ out)
{
    __shared__ __align__(16) unsigned short Bls[4][8][512];  // 32 KB B panel

    const int tid = threadIdx.x;
    const int bx = blockIdx.x;   // 0..3
    const int by = blockIdx.y;   // 0..127
    const int n0 = bx * 64;

    const int w    = tid >> 6;
    const int lane = tid & 63;
    const int col  = lane & 15;
    const int quad = lane >> 4;

    #pragma unroll
    for (int kk = 0; kk < 8; kk++)
        gload_lds16((const unsigned short*)woutT +
                        (size_t)(n0 + w * 16 + col) * 256 + kk * 32 + quad * 8,
                    &Bls[w][kk][0]);
    __syncthreads();

    const int T0 = by * 128 + w * 32;

    f4v acc[2][4] = {{{0.f,0.f,0.f,0.f}, {0.f,0.f,0.f,0.f},
                      {0.f,0.f,0.f,0.f}, {0.f,0.f,0.f,0.f}},
                     {{0.f,0.f,0.f,0.f}, {0.f,0.f,0.f,0.f},
                      {0.f,0.f,0.f,0.f}, {0.f,0.f,0.f,0.f}}};

    #pragma unroll
    for (int kk = 0; kk < 8; kk++) {
        const s8v av0 = *(const s8v*)((const unsigned short*)ctx +
                        (size_t)(T0 + col) * 256 + kk * 32 + quad * 8);
        const s8v av1 = *(const s8v*)((const unsigned short*)ctx +
                        (size_t)(T0 + 16 + col) * 256 + kk * 32 + quad * 8);
        #pragma unroll
        for (int c = 0; c < 4; c++) {
            const s8v bv = *(const s8v*)&Bls[c][kk][lane * 8];
            acc[0][c] = __builtin_amdgcn_mfma_f32_16x16x32_bf16(av0, bv, acc[0][c], 0, 0, 0);
            acc[1][c] = __builtin_amdgcn_mfma_f32_16x16x32_bf16(av1, bv, acc[1][c], 0, 0, 0);
        }
    }

    #pragma unroll
    for (int g = 0; g < 2; g++) {
        #pragma unroll
        for (int c = 0; c < 4; c++) {
            const int n = n0 + c * 16 + col;
            const float bias = bo_f[n];
            #pragma unroll
            for (int r = 0; r < 4; r++)
                out[(size_t)(T0 + g * 16 + quad * 4 + r) * 256 + n] =
                    acc[g][c][r] + bias;
        }
    }
}

// ---------------------------------------------------------------------------
extern "C" void kernel_launch(void* const* d_in, const int* in_sizes, int n_in,
                              void* d_out, int out_size, void* d_ws, size_t ws_size,
                              hipStream_t stream)
{
    const void* x    = d_in[0];
    const void* Wqkv = d_in[1];
    const void* bqkv = d_in[2];
    const void* Wout = d_in[3];
    const void* bout = d_in[4];
    float* out = (float*)d_out;   // reference output dtype: float32

    // ws (bf16 elems): q, k, vT, ctx (4.19M each) | wqkvT 196608 | woutT 65536
    // then fp32 bq_f[3072], bo_f[256]. Total ~34.1 MB.
    // xb (bf16 copy of x, 4.19M elems) ALIASES ctx: consumed by k_qkv_rope
    // before k_attn writes ctx.
    const size_t NQ = (size_t)8 * 8 * 2048 * 32;
    bf16* q_ws   = (bf16*)d_ws;
    bf16* k_ws   = q_ws + NQ;
    bf16* vT_ws  = k_ws + NQ;
    bf16* ctx    = vT_ws + NQ;
    bf16* xb     = ctx;                 // alias (see above)
    bf16* wqkvT  = ctx + NQ;
    bf16* woutT  = wqkvT + (size_t)768 * 256;
    float* bq_f  = (float*)(woutT + (size_t)256 * 256);
    float* bo_f  = bq_f + 3072;

    k_prep    <<<2048,          256, 0, stream>>>(x, Wqkv, bqkv, Wout, bout,
                                                  wqkvT, woutT, bq_f, bo_f, xb);
    k_qkv_rope<<<dim3(12, 128), 256, 0, stream>>>(xb, wqkvT, bq_f,
                                                  q_ws, k_ws, vT_ws);
    k_attn    <<<1024,          256, 0, stream>>>(q_ws, k_ws, vT_ws, ctx);
    k_outproj <<<dim3(4, 128),  256, 0, stream>>>(ctx, woutT, bo_f, out);
}

// Round 15
// 147.802 us; speedup vs baseline: 1.0137x; 1.0137x over previous
//
#include <hip/hip_runtime.h>
#include <hip/hip_bf16.h>
#include <math.h>

typedef __hip_bfloat16 bf16;
using s8v = __attribute__((ext_vector_type(8))) short;   // 8 bf16 (4 VGPRs)
using f4v = __attribute__((ext_vector_type(4))) float;   // 4 fp32
using u32x2 = __attribute__((ext_vector_type(2))) unsigned int;

#if __has_builtin(__builtin_amdgcn_exp2f)
#define EXP2(x) __builtin_amdgcn_exp2f(x)
#else
#define EXP2(x) exp2f(x)
#endif

__device__ __forceinline__ float bfb2f(unsigned short u) {
    return __uint_as_float(((unsigned int)u) << 16);
}
// RNE (output / ws paths)
__device__ __forceinline__ unsigned short f2bfb(float f) {
    unsigned int u = __float_as_uint(f);
    unsigned int r = (u + 0x7fffu + ((u >> 16) & 1u)) >> 16;
    return (unsigned short)r;
}
// RNE pack: 2 fp32 -> u32 of 2 bf16 (bit-identical to scalar f2bfb pair)
__device__ __forceinline__ unsigned int packbf2_rne(float a, float b) {
    return (unsigned int)f2bfb(a) | ((unsigned int)f2bfb(b) << 16);
}
// round-half-up pack via v_perm_b32 (3 VALU) — P path only (exp outputs)
__device__ __forceinline__ unsigned int packbf2(float a, float b) {
    return __builtin_amdgcn_perm(__float_as_uint(b) + 0x8000u,
                                 __float_as_uint(a) + 0x8000u,
                                 0x07060302u);
}
// 4 u32 words -> 8 bf16 fragment
__device__ __forceinline__ s8v mk8(unsigned int a, unsigned int b,
                                   unsigned int c, unsigned int d) {
    union { unsigned int u[4]; s8v v; } x;
    x.u[0] = a; x.u[1] = b; x.u[2] = c; x.u[3] = d;
    return x.v;
}
// permlane32_swap then permlane16_swap on a register pair (gfx950 builtins,
// fi=false bound_ctrl=false). Verified r22 (absmax unchanged).
__device__ __forceinline__ void plswap(unsigned int& a, unsigned int& b) {
    u32x2 t = __builtin_amdgcn_permlane32_swap(a, b, false, false);
    u32x2 u = __builtin_amdgcn_permlane16_swap(t.x, t.y, false, false);
    a = u.x;
    b = u.y;
}

// async global->LDS, 16B per lane: LDS dest = wave-uniform base + lane*16,
// global src = per-lane address (m173 pattern: src addresses encode layout).
__device__ __forceinline__ void gload_lds16(const void* g, void* l) {
    __builtin_amdgcn_global_load_lds(
        (const __attribute__((address_space(1))) unsigned int*)g,
        (__attribute__((address_space(3))) unsigned int*)l, 16, 0, 0);
}

// Per-block input-dtype sniff (proved rounds 4-10: inputs are fp32).
// Coalesced (r16): 4 x uint4 per lane, same decision function.
__device__ __forceinline__ int sniff_fp32(const void* p, int tid, int* s_flag)
{
    if (tid == 0) *s_flag = 0;
    __syncthreads();
    const uint4* u = (const uint4*)p;
    int local = 0;
    #pragma unroll
    for (int i = 0; i < 4; i++) {
        const uint4 v = u[i * 256 + tid];
        if ((v.x & 0x7F80u) == 0x7F80u) local = 1;
        if ((v.y & 0x7F80u) == 0x7F80u) local = 1;
        if ((v.z & 0x7F80u) == 0x7F80u) local = 1;
        if ((v.w & 0x7F80u) == 0x7F80u) local = 1;
    }
    if (local) atomicOr(s_flag, 1);
    __syncthreads();
    return *s_flag;
}

// ---------------------------------------------------------------------------
// Kernel 0: one-time prep. UNCHANGED from r24.
// ---------------------------------------------------------------------------
__global__ __launch_bounds__(256)
void k_prep(const void* __restrict__ x, const void* __restrict__ Wqkv,
            const void* __restrict__ bqkv, const void* __restrict__ Wout,
            const void* __restrict__ bout,
            bf16* __restrict__ wqkvT, bf16* __restrict__ woutT,
            float* __restrict__ bq_f, float* __restrict__ bo_f,
            bf16* __restrict__ xb)
{
    __shared__ int sf;
    const int bid = blockIdx.x;
    const int tid = threadIdx.x;
    if (bid < 768) {
        const int f = sniff_fp32(Wqkv, tid, &sf);
        unsigned short v = f ? f2bfb(((const float*)Wqkv)[(size_t)tid * 768 + bid])
                             : ((const unsigned short*)Wqkv)[(size_t)tid * 768 + bid];
        ((unsigned short*)wqkvT)[(size_t)bid * 256 + tid] = v;
        if (bid < 12) {
            const int i = bid * 256 + tid;
            bq_f[i] = f ? ((const float*)bqkv)[i]
                        : bfb2f(((const unsigned short*)bqkv)[i]);
        }
    } else if (bid < 1024) {
        const int n = bid - 768;
        const int f = sniff_fp32(Wout, tid, &sf);
        unsigned short v = f ? f2bfb(((const float*)Wout)[(size_t)tid * 256 + n])
                             : ((const unsigned short*)Wout)[(size_t)tid * 256 + n];
        ((unsigned short*)woutT)[(size_t)n * 256 + tid] = v;
        if (n == 0)
            bo_f[tid] = f ? ((const float*)bout)[tid]
                          : bfb2f(((const unsigned short*)bout)[tid]);
    } else {
        // x: 4,194,304 elems; 1024 blocks x 256 thr x 16 elems
        const int f = sniff_fp32(x, tid, &sf);
        if (f) {
            // coalesced: lane-stride-16B float4 reads, lane-stride-8B stores
            const size_t cb = (size_t)(bid - 1024) * 4096;
            #pragma unroll
            for (int i = 0; i < 4; i++) {
                const size_t e = cb + (size_t)i * 1024 + tid * 4;
                const float4 v = *(const float4*)((const float*)x + e);
                ushort4 o4;
                o4.x = f2bfb(v.x);
                o4.y = f2bfb(v.y);
                o4.z = f2bfb(v.z);
                o4.w = f2bfb(v.w);
                *(ushort4*)((unsigned short*)xb + e) = o4;
            }
        } else {
            const size_t base = (size_t)(bid - 1024) * 4096 + (size_t)tid * 16;
            const uint4* xu = (const uint4*)((const unsigned short*)x + base);
            uint4* dp = (uint4*)((unsigned short*)xb + base);
            dp[0] = xu[0];
            dp[1] = xu[1];
        }
    }
}

// ---------------------------------------------------------------------------
// Kernel 1 (MFMA): qkv = xb @ Wqkv + bqkv ; RoPE(q,k).
// q scale folds log2(e) (r24). UNCHANGED. grid = (12, 128).
// ---------------------------------------------------------------------------
__global__ __launch_bounds__(256)
void k_qkv_rope(const bf16* __restrict__ xb, const bf16* __restrict__ wqkvT,
                const float* __restrict__ bq_f,
                bf16* __restrict__ q_ws, bf16* __restrict__ k_ws,
                bf16* __restrict__ vT_ws)
{
    __shared__ __align__(16) unsigned short Bls[4][8][512];  // 32 KB B panel
    __shared__ __align__(16) unsigned short Tls[4][1536];    // 12 KB

    const int tid = threadIdx.x;
    const int bx = blockIdx.x;   // N tile 0..11
    const int by = blockIdx.y;   // 128-row M tile 0..127
    const int n0 = bx * 64;

    const int w    = tid >> 6;
    const int lane = tid & 63;
    const int col  = lane & 15;
    const int quad = lane >> 4;
    const int which = n0 >> 8;             // 0=q,1=k,2=v (block-uniform)
    const int b     = (by * 128) >> 11;    // batch (block-uniform)
    unsigned short* Tw = Tls[w];

    // stage B panel: wave w stages c=w, all kk.
    #pragma unroll
    for (int kk = 0; kk < 8; kk++)
        gload_lds16((const unsigned short*)wqkvT +
                        (size_t)(n0 + w * 16 + col) * 256 + kk * 32 + quad * 8,
                    &Bls[w][kk][0]);
    __syncthreads();

    const int T0 = by * 128 + w * 32;      // wave's 32-row band

    f4v acc[2][4] = {{{0.f,0.f,0.f,0.f}, {0.f,0.f,0.f,0.f},
                      {0.f,0.f,0.f,0.f}, {0.f,0.f,0.f,0.f}},
                     {{0.f,0.f,0.f,0.f}, {0.f,0.f,0.f,0.f},
                      {0.f,0.f,0.f,0.f}, {0.f,0.f,0.f,0.f}}};

    #pragma unroll
    for (int kk = 0; kk < 8; kk++) {
        const s8v av0 = *(const s8v*)((const unsigned short*)xb +
                        (size_t)(T0 + col) * 256 + kk * 32 + quad * 8);
        const s8v av1 = *(const s8v*)((const unsigned short*)xb +
                        (size_t)(T0 + 16 + col) * 256 + kk * 32 + quad * 8);
        #pragma unroll
        for (int c = 0; c < 4; c++) {
            const s8v bv = *(const s8v*)&Bls[c][kk][lane * 8];
            acc[0][c] = __builtin_amdgcn_mfma_f32_16x16x32_bf16(av0, bv, acc[0][c], 0, 0, 0);
            acc[1][c] = __builtin_amdgcn_mfma_f32_16x16x32_bf16(av1, bv, acc[1][c], 0, 0, 0);
        }
    }

    #pragma unroll
    for (int g = 0; g < 2; g++) {
        const int t_base = ((by * 128) & 2047) + w * 32 + g * 16;

        if (which == 2) {
            // V: LDS patch [n_local][24] (packed b64 RNE), then 32B rows of vT
            #pragma unroll
            for (int c = 0; c < 4; c++) {
                const int nl = c * 16 + col;
                const float bias = bq_f[n0 + nl];
                uint2 ww;
                ww.x = packbf2_rne(acc[g][c][0] + bias, acc[g][c][1] + bias);
                ww.y = packbf2_rne(acc[g][c][2] + bias, acc[g][c][3] + bias);
                *(uint2*)(Tw + nl * 24 + quad * 4) = ww;
            }
            const int ng = n0 + lane;
            const int h = (ng & 255) >> 5;
            const int d = ng & 31;
            const s8v t0 = *(const s8v*)&Tw[lane * 24];
            const s8v t1 = *(const s8v*)&Tw[lane * 24 + 8];
            unsigned short* dp = (unsigned short*)vT_ws +
                ((size_t)(b * 8 + h) * 32 + d) * 2048 + t_base;
            *(s8v*)dp = t0;
            *(s8v*)(dp + 8) = t1;
        } else {
            // q/k: RoPE in regs, LDS patch [t_local][80], 32B stores
            #pragma unroll
            for (int c = 0; c < 4; c++) {
                const int nl = c * 16 + col;
                const int d = (n0 + nl) & 31;
                const float bias = bq_f[n0 + nl];
                const float frev = __expf(-0.28782314f * (float)(d & ~1))
                                 * 0.15915494309189535f;
                #pragma unroll
                for (int r = 0; r < 4; r++) {
                    const float v = acc[g][c][r] + bias;
                    const float vp = __shfl_xor(v, 1);
                    const int t = t_base + quad * 4 + r;
                    float rev = (float)t * frev;
                    rev -= floorf(rev);
                    const float ang = rev * 6.283185307179586f;
                    const float sn = __sinf(ang);
                    const float cs = __cosf(ang);
                    float o = (d & 1) ? (v * cs + vp * sn)
                                      : (v * cs - vp * sn);
                    // q: 1/sqrt(32) * log2(e) so attn uses bare 2^x
                    if (which == 0) o *= 0.25503487021228657f;
                    Tw[(quad * 4 + r) * 80 + nl] = f2bfb(o);
                }
            }
            const int row = lane >> 2;
            const int ch  = lane & 3;
            const int ng  = n0 + ch * 16;
            const int h   = (ng & 255) >> 5;
            const int d   = ng & 31;
            const int t   = t_base + row;
            const s8v t0 = *(const s8v*)&Tw[row * 80 + ch * 16];
            const s8v t1 = *(const s8v*)&Tw[row * 80 + ch * 16 + 8];
            unsigned short* dp = (unsigned short*)(which ? k_ws : q_ws) +
                ((size_t)(b * 8 + h) * 2048 + t) * 32 + d;
            *(s8v*)dp = t0;
            *(s8v*)(dp + 8) = t1;
        }
        // Tls reuse across g is safe: wave-private buffer, DS ops in-order.
    }
}

// ---------------------------------------------------------------------------
// Kernel 2: causal flash attention. r26 = r24 RESTORED VERBATIM (measured
// best, 148.07us total): 2048x256, 4 waves x 16 q, un-paired longest-first,
// K/V LDS fragment cache (dbuf), permlane P-transpose, P = 2^S (log2e
// pre-folded into q). r25's 128-q restructure regressed (+1.8us): halving
// block-iters lengthened the per-wave serial chain — same invariant as r20.
// The ~40us here is the latency floor of the stage/barrier/MFMA/exp chain
// at 16 waves/CU; both redundancy-cutting restructures traded against the
// parallelism that hides it. LDS 16384 B.
// ---------------------------------------------------------------------------
__global__ __launch_bounds__(256, 4)
void k_attn(const bf16* __restrict__ q_ws, const bf16* __restrict__ k_ws,
            const bf16* __restrict__ vT_ws, bf16* __restrict__ ctx)
{
    // KV fragment cache: [dbuf][chunk][1024B]. chunks 0-3 = kf0..3,
    // 4-7 = v00,v10,v01,v11. Frag read = base + lane*16 (linear).
    __shared__ __align__(16) unsigned short KVls[2][8][512];  // 16 KB

    const int tid  = threadIdx.x;
    const int w    = tid >> 6;
    const int lane = tid & 63;
    const int col  = lane & 15;
    const int quad = lane >> 4;

    const int idx = blockIdx.x;           // 0..2047
    const int bh  = idx & 63;             // batch*8+head; XCD pin = bh&7
    const int mb  = 31 - (idx >> 6);      // q-tile, longest blocks first
    const int T0  = mb * 64 + w * 16;

    const bf16* qb = q_ws  + (size_t)bh * 65536;
    const bf16* kb = k_ws  + (size_t)bh * 65536;
    const bf16* vb = vT_ws + (size_t)bh * 65536;

    const bf16* kg = kb + (size_t)(w * 16 + col) * 32 + quad * 8;
    const bf16* vg = vb + (size_t)(col + (w & 1) * 16) * 2048
                        + (w >> 1) * 32 + quad * 8;

    const s8v qa = *(const s8v*)(qb + (size_t)(T0 + col) * 32 + quad * 8);

    f4v o0 = {0.f,0.f,0.f,0.f}, o1 = {0.f,0.f,0.f,0.f};
    float lp[4] = {0.f,0.f,0.f,0.f};

    // prologue: stage tile 0 into buf 0
    gload_lds16(kg, &KVls[0][w][0]);
    gload_lds16(vg, &KVls[0][4 + w][0]);
    __syncthreads();

    int cur = 0;
    for (int kt = 0; kt <= mb; kt++) {
        const int s0 = kt * 64;

        // stage next tile into the other buffer
        if (kt < mb) {
            gload_lds16(kg + (size_t)(kt + 1) * 2048, &KVls[cur ^ 1][w][0]);
            gload_lds16(vg + (kt + 1) * 64,           &KVls[cur ^ 1][4 + w][0]);
        }

        // fragment reads: linear lane*16, conflict-free
        const s8v kf0 = *(const s8v*)&KVls[cur][0][lane * 8];
        const s8v kf1 = *(const s8v*)&KVls[cur][1][lane * 8];
        const s8v kf2 = *(const s8v*)&KVls[cur][2][lane * 8];
        const s8v kf3 = *(const s8v*)&KVls[cur][3][lane * 8];
        const s8v v00 = *(const s8v*)&KVls[cur][4][lane * 8];
        const s8v v10 = *(const s8v*)&KVls[cur][5][lane * 8];
        const s8v v01 = *(const s8v*)&KVls[cur][6][lane * 8];
        const s8v v11 = *(const s8v*)&KVls[cur][7][lane * 8];

        const f4v z = {0.f, 0.f, 0.f, 0.f};
        // swapped operand order: lane holds S[q=col][s = s0+c*16+quad*4+r]
        f4v s[4];
        s[0] = __builtin_amdgcn_mfma_f32_16x16x32_bf16(kf0, qa, z, 0, 0, 0);
        s[1] = __builtin_amdgcn_mfma_f32_16x16x32_bf16(kf1, qa, z, 0, 0, 0);
        s[2] = __builtin_amdgcn_mfma_f32_16x16x32_bf16(kf2, qa, z, 0, 0, 0);
        s[3] = __builtin_amdgcn_mfma_f32_16x16x32_bf16(kf3, qa, z, 0, 0, 0);

        // causal mask (diagonal tile only)
        if (kt == mb) {
            #pragma unroll
            for (int c = 0; c < 4; c++) {
                const int sbase = s0 + c * 16 + quad * 4;
                #pragma unroll
                for (int r = 0; r < 4; r++)
                    if (sbase + r > T0 + col) s[c][r] = -INFINITY;
            }
        }

        // P = 2^S (log2e pre-folded into q) + lane-local row-sum + pack
        unsigned int pw[8];
        #pragma unroll
        for (int c = 0; c < 4; c++) {
            const float p0 = EXP2(s[c][0]);
            const float p1 = EXP2(s[c][1]);
            const float p2 = EXP2(s[c][2]);
            const float p3 = EXP2(s[c][3]);
            lp[0] += p0; lp[1] += p1; lp[2] += p2; lp[3] += p3;
            pw[c * 2]     = packbf2(p0, p1);
            pw[c * 2 + 1] = packbf2(p2, p3);
        }

        // in-register transpose to PV A-fragments (r22-verified):
        // pw[0..3] = pa0 words 0..3, pw[4..7] = pa1 words 0..3.
        plswap(pw[0], pw[2]);
        plswap(pw[1], pw[3]);
        plswap(pw[4], pw[6]);
        plswap(pw[5], pw[7]);
        const s8v pa0 = mk8(pw[0], pw[1], pw[2], pw[3]);
        const s8v pa1 = mk8(pw[4], pw[5], pw[6], pw[7]);

        // PV
        o0 = __builtin_amdgcn_mfma_f32_16x16x32_bf16(pa0, v00, o0, 0, 0, 0);
        o1 = __builtin_amdgcn_mfma_f32_16x16x32_bf16(pa0, v10, o1, 0, 0, 0);
        o0 = __builtin_amdgcn_mfma_f32_16x16x32_bf16(pa1, v01, o0, 0, 0, 0);
        o1 = __builtin_amdgcn_mfma_f32_16x16x32_bf16(pa1, v11, o1, 0, 0, 0);

        // barrier: (a) drains this wave's stage loads (vmcnt) so next iter's
        // frag reads are safe; (b) orders buffer reuse across waves.
        __syncthreads();
        cur ^= 1;
    }

    // Row sums: lane-local partials -> cross-quad reduce.
    float rs = lp[0] + lp[1] + lp[2] + lp[3];
    rs += __shfl_xor(rs, 16);
    rs += __shfl_xor(rs, 32);

    const int b = bh >> 3;
    const int h = bh & 7;
    unsigned short* cp = (unsigned short*)ctx;
    #pragma unroll
    for (int r = 0; r < 4; r++) {
        // output row q = quad*4+r; its row-sum lives in lane quad*4+r
        const float inv = 1.0f / __shfl(rs, quad * 4 + r);
        const float e0 = o0[r] * inv;
        const float e1 = o1[r] * inv;
        const int t = T0 + quad * 4 + r;
        unsigned short* dst = cp + (size_t)(b * 2048 + t) * 256 + h * 32;
        dst[col]      = f2bfb(e0);
        dst[col + 16] = f2bfb(e1);
    }
}

// ---------------------------------------------------------------------------
// Kernel 3 (MFMA): out = ctx @ Wout + bout (M=16384,N=256,K=256), fp32 out.
// 32-row waves (r19). UNCHANGED. grid = (4, 128).
// ---------------------------------------------------------------------------
__global__ __launch_bounds__(256)
void k_outproj(const bf16* __restrict__ ctx, const bf16* __restrict__ woutT,
               const float* __restrict__ bo_f, float* __restrict__ out)
{
    __shared__ __align__(16) unsigned short Bls[4][8][512];  // 32 KB B panel

    const int tid = threadIdx.x;
    const int bx = blockIdx.x;   // 0..3
    const int by = blockIdx.y;   // 0..127
    const int n0 = bx * 64;

    const int w    = tid >> 6;
    const int lane = tid & 63;
    const int col  = lane & 15;
    const int quad = lane >> 4;

    #pragma unroll
    for (int kk = 0; kk < 8; kk++)
        gload_lds16((const unsigned short*)woutT +
                        (size_t)(n0 + w * 16 + col) * 256 + kk * 32 + quad * 8,
                    &Bls[w][kk][0]);
    __syncthreads();

    const int T0 = by * 128 + w * 32;

    f4v acc[2][4] = {{{0.f,0.f,0.f,0.f}, {0.f,0.f,0.f,0.f},
                      {0.f,0.f,0.f,0.f}, {0.f,0.f,0.f,0.f}},
                     {{0.f,0.f,0.f,0.f}, {0.f,0.f,0.f,0.f},
                      {0.f,0.f,0.f,0.f}, {0.f,0.f,0.f,0.f}}};

    #pragma unroll
    for (int kk = 0; kk < 8; kk++) {
        const s8v av0 = *(const s8v*)((const unsigned short*)ctx +
                        (size_t)(T0 + col) * 256 + kk * 32 + quad * 8);
        const s8v av1 = *(const s8v*)((const unsigned short*)ctx +
                        (size_t)(T0 + 16 + col) * 256 + kk * 32 + quad * 8);
        #pragma unroll
        for (int c = 0; c < 4; c++) {
            const s8v bv = *(const s8v*)&Bls[c][kk][lane * 8];
            acc[0][c] = __builtin_amdgcn_mfma_f32_16x16x32_bf16(av0, bv, acc[0][c], 0, 0, 0);
            acc[1][c] = __builtin_amdgcn_mfma_f32_16x16x32_bf16(av1, bv, acc[1][c], 0, 0, 0);
        }
    }

    #pragma unroll
    for (int g = 0; g < 2; g++) {
        #pragma unroll
        for (int c = 0; c < 4; c++) {
            const int n = n0 + c * 16 + col;
            const float bias = bo_f[n];
            #pragma unroll
            for (int r = 0; r < 4; r++)
                out[(size_t)(T0 + g * 16 + quad * 4 + r) * 256 + n] =
                    acc[g][c][r] + bias;
        }
    }
}

// ---------------------------------------------------------------------------
extern "C" void kernel_launch(void* const* d_in, const int* in_sizes, int n_in,
                              void* d_out, int out_size, void* d_ws, size_t ws_size,
                              hipStream_t stream)
{
    const void* x    = d_in[0];
    const void* Wqkv = d_in[1];
    const void* bqkv = d_in[2];
    const void* Wout = d_in[3];
    const void* bout = d_in[4];
    float* out = (float*)d_out;   // reference output dtype: float32

    // ws (bf16 elems): q, k, vT, ctx (4.19M each) | wqkvT 196608 | woutT 65536
    // then fp32 bq_f[3072], bo_f[256]. Total ~34.1 MB.
    // xb (bf16 copy of x, 4.19M elems) ALIASES ctx: consumed by k_qkv_rope
    // before k_attn writes ctx.
    const size_t NQ = (size_t)8 * 8 * 2048 * 32;
    bf16* q_ws   = (bf16*)d_ws;
    bf16* k_ws   = q_ws + NQ;
    bf16* vT_ws  = k_ws + NQ;
    bf16* ctx    = vT_ws + NQ;
    bf16* xb     = ctx;                 // alias (see above)
    bf16* wqkvT  = ctx + NQ;
    bf16* woutT  = wqkvT + (size_t)768 * 256;
    float* bq_f  = (float*)(woutT + (size_t)256 * 256);
    float* bo_f  = bq_f + 3072;

    k_prep    <<<2048,          256, 0, stream>>>(x, Wqkv, bqkv, Wout, bout,
                                                  wqkvT, woutT, bq_f, bo_f, xb);
    k_qkv_rope<<<dim3(12, 128), 256, 0, stream>>>(xb, wqkvT, bq_f,
                                                  q_ws, k_ws, vT_ws);
    k_attn    <<<2048,          256, 0, stream>>>(q_ws, k_ws, vT_ws, ctx);
    k_outproj <<<dim3(4, 128),  256, 0, stream>>>(ctx, woutT, bo_f, out);
}